// Round 2
// 377.260 us; speedup vs baseline: 1.1156x; 1.1156x over previous
//
#include <hip/hip_runtime.h>
#include <hip/hip_bf16.h>
#include <cstdio>

typedef __bf16 bf16_t;
typedef __bf16 bf16x8 __attribute__((ext_vector_type(8)));
typedef __bf16 bf16x4 __attribute__((ext_vector_type(4)));
typedef float  f32x16 __attribute__((ext_vector_type(16)));

#define TILE_E (256 * 64)   // elements of one K-tile (256 rows x 64 cols bf16) = 32 KiB

// ---- merged f32 -> bf16 convert for x, Wa, Wo (one dispatch) ---------------
__global__ __launch_bounds__(256)
void cvt_all(const float* __restrict__ x,  bf16_t* __restrict__ xb,  int nX,
             const float* __restrict__ Wa, bf16_t* __restrict__ Wab,
             const float* __restrict__ Wo, bf16_t* __restrict__ Wob, int nW)
{
    const int nT = nX + 2 * nW;
    for (int i = (blockIdx.x * 256 + threadIdx.x) * 4; i < nT; i += gridDim.x * 256 * 4) {
        const float* src; bf16_t* dst; int off;
        if (i < nX)            { src = x;  dst = xb;  off = i; }
        else if (i < nX + nW)  { src = Wa; dst = Wab; off = i - nX; }
        else                   { src = Wo; dst = Wob; off = i - nX - nW; }
        const float4 v = *(const float4*)(src + off);
        bf16x4 o;
        o[0] = (bf16_t)v.x; o[1] = (bf16_t)v.y; o[2] = (bf16_t)v.z; o[3] = (bf16_t)v.w;
        *(bf16x4*)(dst + off) = o;
    }
}

// ---- 256x256 8-phase GEMM core ---------------------------------------------
// LDS tile: 256 rows x 64 cols bf16, row = 128 B = 8 chunks of 16 B.
// Swizzle: logical chunk c of row r lives at physical slot c ^ (r & 7).
// Staging pre-swizzles the per-lane GLOBAL src addr; LDS dest stays linear
// (wave-uniform base + lane*16 — HW rule for global_load_lds); reads apply
// the same XOR.
//
// LDS region lifetimes per iteration (all reads fenced by each phase's
// lgkmcnt(0) which precedes that phase's end barrier):
//   cur A rows 0..127 & 128..255 : read phases 0 AND 2  -> overwrite >= ph3
//   cur B rows 0..127 (wn=0,1)   : read phases 0,1      -> overwrite >= ph2
//   cur B rows 128..255 (wn=2,3) : read phases 0,1      -> overwrite >= ph2
//   other buffer                  : not read this iter   -> ph0 ok
// Stage schedule: ph0: A1(t+1)->other ; ph2: B0(t+2)->cur ;
//                 ph3: A0(t+2)->cur, B1(t+2)->cur.           (R1 bug: A0 was
// at ph1, racing phase-2 A reads -> absmax 0.31. Fixed here.)

template<int K>
__device__ __forceinline__ void stage_half(
    const bf16_t* __restrict__ src, bf16_t* lds_tile,
    int half, int kt, int w, int l)
{
    const int r0 = half * 128 + w * 8 + (l >> 3);
    const int c8 = ((l & 7) ^ (l >> 3)) * 8;          // pre-swizzled source chunk
#pragma unroll
    for (int rr = 0; rr < 2; rr++) {
        __builtin_amdgcn_global_load_lds(
            (const __attribute__((address_space(1))) void*)
                (src + (size_t)(r0 + rr * 64) * K + (size_t)kt * 64 + c8),
            (__attribute__((address_space(3))) void*)
                (lds_tile + (half * 128 + rr * 64 + w * 8) * 64),
            16, 0, 0);
    }
}

// frag reads: row r = off + f*32 + (l&31); logical chunk = ks*2 + (l>>5);
// r&7 == l&7 (off, f*32 are multiples of 8)
#define RDF_A(f, ks) (*(const bf16x8*)&sAc[(aoff + (f) * 32 + l31) * 64 + ((((ks) * 2 + l5) ^ lo7) * 8)])
#define RDF_B(f, ks) (*(const bf16x8*)&sBc[(boff + (f) * 32 + l31) * 64 + ((((ks) * 2 + l5) ^ lo7) * 8)])

#define MFMA_QUAD(BV, MB, NB)                                              \
    _Pragma("unroll") for (int ks = 0; ks < 4; ks++)                       \
    _Pragma("unroll") for (int mi = 0; mi < 2; mi++)                       \
        acc[(MB) + mi][NB] = __builtin_amdgcn_mfma_f32_32x32x16_bf16(      \
            ar[mi][ks], BV[ks], acc[(MB) + mi][NB], 0, 0, 0);

#define LGKM0_FENCE                                        \
    asm volatile("s_waitcnt lgkmcnt(0)" ::: "memory");     \
    __builtin_amdgcn_sched_barrier(0);

template<int K>
__device__ __forceinline__ void gemm256_core(
    const bf16_t* __restrict__ Ab, const bf16_t* __restrict__ Bb,
    f32x16 (&acc)[4][2], int w, int l, int wm, int wn)
{
    __shared__ bf16_t sA[2 * TILE_E];     // 64 KiB
    __shared__ bf16_t sB[2 * TILE_E];     // 64 KiB
    constexpr int NKT = K / 64;

    const int l31 = l & 31, l5 = l >> 5, lo7 = l & 7;
    const int aoff = wm * 128, boff = wn * 64;

    // prologue: tile0 {A0,B0,B1,A1}, tile1 {A0,B0,B1} = 14 loads/thread
    stage_half<K>(Ab, sA, 0, 0, w, l);
    stage_half<K>(Bb, sB, 0, 0, w, l);
    stage_half<K>(Bb, sB, 1, 0, w, l);
    stage_half<K>(Ab, sA, 1, 0, w, l);
    stage_half<K>(Ab, sA + TILE_E, 0, 1, w, l);
    stage_half<K>(Bb, sB + TILE_E, 0, 1, w, l);
    stage_half<K>(Bb, sB + TILE_E, 1, 1, w, l);

    bf16x8 ar[2][4], bl[4], bh[4];

#pragma unroll 2
    for (int t = 0; t < NKT; ++t) {
        bf16_t* sAc = sA + (t & 1) * TILE_E;
        bf16_t* sBc = sB + (t & 1) * TILE_E;
        bf16_t* sAn = sA + ((t + 1) & 1) * TILE_E;

        // tile boundary: tile t fully resident; 3 newest half-tiles
        // (B0/A0/B1 of t+2-lineage, 6 loads) may stay in flight.
        if (t + 1 < NKT) { asm volatile("s_waitcnt vmcnt(6)" ::: "memory"); }
        else             { asm volatile("s_waitcnt vmcnt(0)" ::: "memory"); }
        __builtin_amdgcn_s_barrier();

        // ---- phase 0 : quad (M-lo, N0); stage A1(t+1) -> other buf ----
#pragma unroll
        for (int mi = 0; mi < 2; mi++)
#pragma unroll
            for (int ks = 0; ks < 4; ks++) ar[mi][ks] = RDF_A(mi, ks);
#pragma unroll
        for (int ks = 0; ks < 4; ks++) bl[ks] = RDF_B(0, ks);
        if (t + 1 < NKT) stage_half<K>(Ab, sAn, 1, t + 1, w, l);
        __builtin_amdgcn_s_barrier();
        LGKM0_FENCE
        __builtin_amdgcn_s_setprio(1);
        MFMA_QUAD(bl, 0, 0)
        __builtin_amdgcn_s_setprio(0);
        __builtin_amdgcn_s_barrier();

        // ---- phase 1 : quad (M-lo, N1); no stage ----
#pragma unroll
        for (int ks = 0; ks < 4; ks++) bh[ks] = RDF_B(1, ks);
        __builtin_amdgcn_s_barrier();
        LGKM0_FENCE
        __builtin_amdgcn_s_setprio(1);
        MFMA_QUAD(bh, 0, 1)
        __builtin_amdgcn_s_setprio(0);
        __builtin_amdgcn_s_barrier();

        // ---- phase 2 : quad (M-hi, N0); stage B0(t+2) -> cur (B dead) ----
#pragma unroll
        for (int mi = 0; mi < 2; mi++)
#pragma unroll
            for (int ks = 0; ks < 4; ks++) ar[mi][ks] = RDF_A(2 + mi, ks);
        if (t + 2 < NKT) stage_half<K>(Bb, sBc, 0, t + 2, w, l);
        __builtin_amdgcn_s_barrier();
        LGKM0_FENCE
        __builtin_amdgcn_s_setprio(1);
        MFMA_QUAD(bl, 2, 0)
        __builtin_amdgcn_s_setprio(0);
        __builtin_amdgcn_s_barrier();

        // ---- phase 3 : stage A0(t+2), B1(t+2) -> cur (A,B dead now) ----
        if (t + 2 < NKT) {
            stage_half<K>(Ab, sAc, 0, t + 2, w, l);
            stage_half<K>(Bb, sBc, 1, t + 2, w, l);
        }
        __builtin_amdgcn_s_barrier();
        __builtin_amdgcn_s_setprio(1);
        MFMA_QUAD(bh, 2, 1)
        __builtin_amdgcn_s_setprio(0);
        __builtin_amdgcn_s_barrier();
    }
}

#define ACC_INIT(acc)                                            \
    _Pragma("unroll") for (int i = 0; i < 4; i++)                \
    _Pragma("unroll") for (int j = 0; j < 2; j++)                \
    _Pragma("unroll") for (int e = 0; e < 16; e++) acc[i][j][e] = 0.f;

// ---- fused key/value GEMM (256^2 tiles) ------------------------------------
__global__ __launch_bounds__(512, 2)
void gemm_kv8(const bf16_t* __restrict__ xb,
              const bf16_t* __restrict__ Wa, const bf16_t* __restrict__ Wo,
              const float* __restrict__ ba, const float* __restrict__ bo,
              bf16_t* __restrict__ key, bf16_t* __restrict__ vT)
{
    constexpr int K = 1024, Nn = 2048, Dd = 1024;
    const int tid = threadIdx.x;
    const int w = tid >> 6, l = tid & 63;
    const int wm = w >> 2, wn = w & 3;

    // XCD swizzle (nwg = 512, %8 == 0 -> bijective)
    const int bid = blockIdx.x;
    const int id  = (bid & 7) * 64 + (bid >> 3);
    const int b   = id >> 6;
    const int rest = id & 63;
    const int tm  = rest & 7;          // m-tile [0,8)
    const int tn  = rest >> 3;         // n-tile [0,8): 0-3 key, 4-7 value
    const bool isK = tn < 4;

    const bf16_t* Ab = xb + (size_t)b * Nn * K + (size_t)tm * 256 * K;
    const bf16_t* Bb = isK ? (Wa + (size_t)tn * 256 * K)
                           : (Wo + (size_t)(tn - 4) * 256 * K);

    f32x16 acc[4][2];
    ACC_INIT(acc)
    gemm256_core<K>(Ab, Bb, acc, w, l, wm, wn);

    // 32x32 C/D: col = lane&31, row = (reg&3) + 8*(reg>>2) + 4*(lane>>5)
    const int l31 = l & 31, l5 = l >> 5;
    if (isK) {
#pragma unroll
        for (int n = 0; n < 2; n++) {
            const int cg = (tn & 3) * 256 + wn * 64 + n * 32 + l31;
            const float bv = ba[cg];
#pragma unroll
            for (int m = 0; m < 4; m++)
#pragma unroll
                for (int rg = 0; rg < 4; rg++) {
                    const int rowg = tm * 256 + wm * 128 + m * 32 + rg * 8 + 4 * l5;
                    bf16_t* p = key + (size_t)b * Nn * Dd + (size_t)rowg * Dd + cg;
#pragma unroll
                    for (int j = 0; j < 4; j++)
                        p[(size_t)j * Dd] = (bf16_t)(acc[m][n][rg * 4 + j] + bv);
                }
        }
    } else {
#pragma unroll
        for (int n = 0; n < 2; n++) {
            const int cg = (tn & 3) * 256 + wn * 64 + n * 32 + l31;
            const float bv = bo[cg];
#pragma unroll
            for (int m = 0; m < 4; m++)
#pragma unroll
                for (int rg = 0; rg < 4; rg++) {
                    const int rowg = tm * 256 + wm * 128 + m * 32 + rg * 8 + 4 * l5;
                    bf16x4 pk;
#pragma unroll
                    for (int j = 0; j < 4; j++) pk[j] = (bf16_t)(acc[m][n][rg * 4 + j] + bv);
                    *(bf16x4*)(vT + (size_t)b * Dd * Nn + (size_t)cg * Nn + rowg) = pk;
                }
        }
    }
}

// ---- scores GEMM: S = (x @ key^T) * scale, bf16 ----------------------------
__global__ __launch_bounds__(512, 2)
void gemm_scores8(const bf16_t* __restrict__ xb, const bf16_t* __restrict__ key,
                  bf16_t* __restrict__ S)
{
    constexpr int K = 1024, Nn = 2048;
    const int tid = threadIdx.x;
    const int w = tid >> 6, l = tid & 63;
    const int wm = w >> 2, wn = w & 3;

    const int bid = blockIdx.x;
    const int id  = (bid & 7) * 64 + (bid >> 3);
    const int b   = id >> 6;
    const int rest = id & 63;
    const int tm  = rest & 7;
    const int tn  = rest >> 3;

    const bf16_t* Ab = xb  + (size_t)b * Nn * K + (size_t)tm * 256 * K;
    const bf16_t* Bb = key + (size_t)b * Nn * K + (size_t)tn * 256 * K;

    f32x16 acc[4][2];
    ACC_INIT(acc)
    gemm256_core<K>(Ab, Bb, acc, w, l, wm, wn);

    const int l31 = l & 31, l5 = l >> 5;
#pragma unroll
    for (int n = 0; n < 2; n++) {
        const int cg = tn * 256 + wn * 64 + n * 32 + l31;
#pragma unroll
        for (int m = 0; m < 4; m++)
#pragma unroll
            for (int rg = 0; rg < 4; rg++) {
                const int rowg = tm * 256 + wm * 128 + m * 32 + rg * 8 + 4 * l5;
                bf16_t* p = S + (size_t)b * Nn * Nn + (size_t)rowg * Nn + cg;
#pragma unroll
                for (int j = 0; j < 4; j++)
                    p[(size_t)j * Nn] = (bf16_t)(acc[m][n][rg * 4 + j] * 0.03125f);
            }
    }
}

// ---- in-place normalizing row softmax (rows of 2048 bf16) ------------------
__global__ __launch_bounds__(256)
void softmax_rows(bf16_t* __restrict__ S)
{
    __shared__ float red[8];
    const int t = threadIdx.x;
    const int w = t >> 6;
    const int lane = t & 63;
    bf16_t* p = S + (size_t)blockIdx.x * 2048;

    bf16x8 v = *(const bf16x8*)&p[t * 8];
    float x[8];
    float m = -1e30f;
#pragma unroll
    for (int i = 0; i < 8; i++) { x[i] = (float)v[i]; m = fmaxf(m, x[i]); }
#pragma unroll
    for (int off = 32; off >= 1; off >>= 1) m = fmaxf(m, __shfl_xor(m, off));
    if (lane == 0) red[w] = m;
    __syncthreads();
    m = fmaxf(fmaxf(red[0], red[1]), fmaxf(red[2], red[3]));

    float s = 0.f;
#pragma unroll
    for (int i = 0; i < 8; i++) { x[i] = __expf(x[i] - m); s += x[i]; }
#pragma unroll
    for (int off = 32; off >= 1; off >>= 1) s += __shfl_xor(s, off);
    if (lane == 0) red[4 + w] = s;
    __syncthreads();
    const float inv = 1.f / (red[4] + red[5] + red[6] + red[7]);

    bf16x8 o;
#pragma unroll
    for (int i = 0; i < 8; i++) o[i] = (bf16_t)(x[i] * inv);
    *(bf16x8*)&p[t * 8] = o;
}

// ---- out GEMM: out = P @ (vT)^T, f32 ---------------------------------------
__global__ __launch_bounds__(512, 2)
void gemm_out8(const bf16_t* __restrict__ P, const bf16_t* __restrict__ vT,
               float* __restrict__ out)
{
    constexpr int K = 2048, Nn = 2048, Dd = 1024;
    const int tid = threadIdx.x;
    const int w = tid >> 6, l = tid & 63;
    const int wm = w >> 2, wn = w & 3;

    // nwg = 256 (%8 == 0)
    const int bid = blockIdx.x;
    const int id  = (bid & 7) * 32 + (bid >> 3);
    const int b   = id >> 5;
    const int rest = id & 31;
    const int tm  = rest & 7;          // [0,8)
    const int tn  = rest >> 3;         // [0,4)

    const bf16_t* Ab = P  + (size_t)b * Nn * Nn + (size_t)tm * 256 * Nn;
    const bf16_t* Bb = vT + (size_t)b * Dd * Nn + (size_t)tn * 256 * Nn;

    f32x16 acc[4][2];
    ACC_INIT(acc)
    gemm256_core<K>(Ab, Bb, acc, w, l, wm, wn);

    const int l31 = l & 31, l5 = l >> 5;
#pragma unroll
    for (int n = 0; n < 2; n++) {
        const int cg = tn * 256 + wn * 64 + n * 32 + l31;
#pragma unroll
        for (int m = 0; m < 4; m++)
#pragma unroll
            for (int rg = 0; rg < 4; rg++) {
                const int rowg = tm * 256 + wm * 128 + m * 32 + rg * 8 + 4 * l5;
                float* p = out + (size_t)b * Nn * Dd + (size_t)rowg * Dd + cg;
#pragma unroll
                for (int j = 0; j < 4; j++)
                    p[(size_t)j * Dd] = acc[m][n][rg * 4 + j];
            }
    }
}

extern "C" void kernel_launch(void* const* d_in, const int* in_sizes, int n_in,
                              void* d_out, int out_size, void* d_ws, size_t ws_size,
                              hipStream_t stream)
{
    const int Bn = 8, Nn = 2048, Dd = 1024;

    const float* x  = (const float*)d_in[0];
    const float* Wa = (const float*)d_in[1];
    const float* ba = (const float*)d_in[2];
    const float* Wo = (const float*)d_in[3];
    const float* bo = (const float*)d_in[4];
    float* out = (float*)d_out;

    const size_t nX = (size_t)Bn * Nn * Dd;
    const size_t nW = (size_t)Dd * Dd;
    const size_t nS = (size_t)Bn * Nn * Nn;

    bf16_t* xb  = (bf16_t*)d_ws;          // [B, N, D] bf16
    bf16_t* Wab = xb + nX;                // [D, D]
    bf16_t* Wob = Wab + nW;               // [D, D]
    bf16_t* key = Wob + nW;               // [B, N, D]
    bf16_t* vT  = key + nX;               // [B, D, N]
    bf16_t* S   = vT + nX;                // [B, N, N]
    const size_t needed = (nX * 3 + nW * 2 + nS) * sizeof(bf16_t);
    if (ws_size < needed)
        fprintf(stderr, "kernel_launch: ws too small: have %zu need %zu\n", ws_size, needed);

    // one merged convert dispatch (x, Wa, Wo)
    cvt_all<<<dim3(18432), dim3(256), 0, stream>>>(x, xb, (int)nX, Wa, Wab, Wo, Wob, (int)nW);

    // key = x@Wa^T+ba ; vT = (x@Wo^T+bo)^T    (512 blocks of 512 thr)
    gemm_kv8<<<dim3(512), dim3(512), 0, stream>>>(xb, Wab, Wob, ba, bo, key, vT);

    // S = (x @ key^T) / 32
    gemm_scores8<<<dim3(512), dim3(512), 0, stream>>>(xb, key, S);

    // P = softmax(S) in place
    softmax_rows<<<dim3(Bn * Nn), dim3(256), 0, stream>>>(S);

    // out = P @ (vT)^T   [B,N,D] f32
    gemm_out8<<<dim3(256), dim3(512), 0, stream>>>(S, vT, out);
}